// Round 1
// baseline (315.862 us; speedup 1.0000x reference)
//
#include <hip/hip_runtime.h>

// VQ pairwise L2, single fused kernel: out[n,k] = ||X[n,:] - E[k,:]||.
// N=65536, K=1024, D=64. One 128x128 output tile per block (4 waves).
// fp32 X/E loaded directly (coalesced float4), converted fp32->bf16 in-reg
// (RNE, identical numerics to the old two-pass version), staged to padded
// LDS (stride 72 bf16 = 144 B, bank-conflict-floor for the ds_read_b128
// fragment pattern); row sum-of-squares computed inline during staging via
// width-8 shuffle reduce; 16x16x32 bf16 MFMA cross term; sqrt epilogue with
// nontemporal fp32 stores. No workspace, no second dispatch.
//
// XCD swizzle (T1): 4096 blocks, 8 XCDs, bid%8 -> XCD under round-robin
// dispatch; remap so each XCD gets a contiguous chunk of tile-space ->
// each X tile (32 KB fp32) is read into ONE XCD L2 instead of all 8.

typedef __attribute__((ext_vector_type(8))) short short8;    // 8 bf16 = 4 VGPR
typedef __attribute__((ext_vector_type(4))) float floatx4;   // MFMA C/D

#define LSTR 72          // padded LDS row stride in bf16 elems (144 B)
#define N_ROWS 65536

__device__ __forceinline__ unsigned short f2bf(float f) {
    unsigned int u = __float_as_uint(f);
    u += 0x7FFFu + ((u >> 16) & 1u);     // round-to-nearest-even
    return (unsigned short)(u >> 16);
}
__device__ __forceinline__ float bf2f(unsigned short h) {
    return __uint_as_float(((unsigned int)h) << 16);
}

__global__ __launch_bounds__(256) void vq_fused(const float* __restrict__ X,
                                                const float* __restrict__ E,
                                                float* __restrict__ out,
                                                int Ktot) {
    __shared__ unsigned short lds[2 * 128 * LSTR];   // A tile then B tile, 36864 B
    __shared__ float s_xsq[128];
    __shared__ float s_esq[128];

    const int tid = threadIdx.x;

    // ---- XCD-aware tile swizzle (bijective: 4096 % 8 == 0) ----
    const int nxb = Ktot >> 7;                 // tiles along K (8)
    const int cpx = gridDim.x >> 3;            // tiles per XCD (512)
    const int bid = blockIdx.x;
    const int swz = (bid & 7) * cpx + (bid >> 3);
    const int bx = swz % nxb;
    const int by = swz / nxb;
    const size_t m0 = (size_t)by * 128;
    const int n0 = bx * 128;

    unsigned short* ldsA = lds;
    unsigned short* ldsB = lds + 128 * LSTR;

    const float* gX = X + m0 * 64;
    const float* gE = E + (size_t)n0 * 64;

    // ---- stage: issue all 16 global float4 loads first (latency overlap) ----
    // 8 threads per row, 32 B (8 floats) per thread; 4 iters cover 128 rows.
    float4 v[8][2];
    #pragma unroll
    for (int it = 0; it < 4; ++it) {
        const int g = it * 256 + tid;
        const int row = g >> 3, c8 = (g & 7) * 8;
        const float* p = gX + row * 64 + c8;
        v[it][0] = *(const float4*)p;
        v[it][1] = *(const float4*)(p + 4);
        const float* q = gE + row * 64 + c8;
        v[4 + it][0] = *(const float4*)q;
        v[4 + it][1] = *(const float4*)(q + 4);
    }

    // ---- convert to bf16, write LDS, inline row-norm (8-lane reduce) ----
    #pragma unroll
    for (int half = 0; half < 2; ++half) {
        unsigned short* dst = half ? ldsB : ldsA;
        float* sq = half ? s_esq : s_xsq;
        #pragma unroll
        for (int it = 0; it < 4; ++it) {
            const int g = it * 256 + tid;
            const int row = g >> 3, c8 = (g & 7) * 8;
            const float* f = (const float*)&v[half * 4 + it][0];
            float s = 0.f;
            short8 pk;
            #pragma unroll
            for (int j = 0; j < 8; ++j) {
                const unsigned short h = f2bf(f[j]);
                const float r = bf2f(h);
                s = fmaf(r, r, s);          // norm from ROUNDED value (matches ref-passing numerics)
                pk[j] = (short)h;
            }
            *(short8*)&dst[row * LSTR + c8] = pk;
            s += __shfl_down(s, 4, 8);
            s += __shfl_down(s, 2, 8);
            s += __shfl_down(s, 1, 8);
            if ((tid & 7) == 0) sq[row] = s;
        }
    }
    __syncthreads();

    // ---- fragments from LDS (same proven layout as before) ----
    const int w = tid >> 6;
    const int lane = tid & 63;
    const int quad = lane >> 4;
    const int l16 = lane & 15;
    const int wm = (w >> 1) * 64;
    const int wn = (w & 1) * 64;

    short8 a0[4], a1[4], b0[4], b1[4];
    #pragma unroll
    for (int t = 0; t < 4; ++t) {
        const int ar = wm + t * 16 + l16;
        a0[t] = *(const short8*)&ldsA[ar * LSTR + quad * 8];
        a1[t] = *(const short8*)&ldsA[ar * LSTR + 32 + quad * 8];
        const int br = wn + t * 16 + l16;
        b0[t] = *(const short8*)&ldsB[br * LSTR + quad * 8];
        b1[t] = *(const short8*)&ldsB[br * LSTR + 32 + quad * 8];
    }

    floatx4 acc[4][4];
    #pragma unroll
    for (int i = 0; i < 4; ++i)
        #pragma unroll
        for (int j = 0; j < 4; ++j)
            acc[i][j] = (floatx4){0.f, 0.f, 0.f, 0.f};

    #pragma unroll
    for (int i = 0; i < 4; ++i)
        #pragma unroll
        for (int j = 0; j < 4; ++j) {
            acc[i][j] = __builtin_amdgcn_mfma_f32_16x16x32_bf16(a0[i], b0[j], acc[i][j], 0, 0, 0);
            acc[i][j] = __builtin_amdgcn_mfma_f32_16x16x32_bf16(a1[i], b1[j], acc[i][j], 0, 0, 0);
        }

    // ---- epilogue: d = sqrt(max(xsq + esq - 2*cross, 0)) ----
    // C/D layout: col = l16, row = quad*4 + r
    #pragma unroll
    for (int i = 0; i < 4; ++i) {
        const int mrow = wm + i * 16 + quad * 4;
        float xq[4];
        #pragma unroll
        for (int r = 0; r < 4; ++r) xq[r] = s_xsq[mrow + r];
        #pragma unroll
        for (int j = 0; j < 4; ++j) {
            const int ncol = wn + j * 16 + l16;
            const float eq = s_esq[ncol];
            float* op = out + (m0 + mrow) * Ktot + (n0 + ncol);
            #pragma unroll
            for (int r = 0; r < 4; ++r) {
                float d = xq[r] + eq - 2.0f * acc[i][j][r];
                d = fmaxf(d, 0.0f);
                __builtin_nontemporal_store(sqrtf(d), op + (size_t)r * Ktot);
            }
        }
    }
}

extern "C" void kernel_launch(void* const* d_in, const int* in_sizes, int n_in,
                              void* d_out, int out_size, void* d_ws, size_t ws_size,
                              hipStream_t stream) {
    const float* X = (const float*)d_in[0];
    const float* E = (const float*)d_in[1];
    float* out = (float*)d_out;
    const int K = in_sizes[1] / 64;   // 1024

    const int tiles = (N_ROWS / 128) * (K / 128);   // 4096
    vq_fused<<<dim3(tiles), dim3(256), 0, stream>>>(X, E, out, K);
}

// Round 3
// 303.697 us; speedup vs baseline: 1.0401x; 1.0401x over previous
//
#include <hip/hip_runtime.h>

// VQ pairwise L2, single fused kernel: out[n,k] = ||X[n,:] - E[k,:]||.
// N=65536, K=1024, D=64. One 128x128 output tile per block (4 waves).
// fp32 X/E loaded directly (coalesced float4), converted fp32->bf16 in-reg
// (RNE), staged to padded LDS (stride 72 bf16 = 144 B); row sum-of-squares
// computed inline during staging (width-8 shuffle reduce); 16x16x32 bf16
// MFMA cross term with SWAPPED operands (E as A-operand, X as B-operand) so
// each lane's 4 acc regs are 4 consecutive OUTPUT COLUMNS -> vectorized
// 16B nontemporal stores (ext-vector floatx4 — HIP float4 struct is
// rejected by __builtin_nontemporal_store). sqrt via raw v_sqrt_f32.
//
// XCD swizzle (T1): 4096 blocks, 8 XCDs; remap so each XCD gets a
// contiguous chunk of tile-space (X tiles read into ONE XCD L2).

typedef __attribute__((ext_vector_type(8))) short short8;    // 8 bf16 = 4 VGPR
typedef __attribute__((ext_vector_type(4))) float floatx4;   // MFMA C/D + stores

#define LSTR 72          // padded LDS row stride in bf16 elems (144 B)
#define N_ROWS 65536

__device__ __forceinline__ unsigned short f2bf(float f) {
    unsigned int u = __float_as_uint(f);
    u += 0x7FFFu + ((u >> 16) & 1u);     // round-to-nearest-even
    return (unsigned short)(u >> 16);
}
__device__ __forceinline__ float bf2f(unsigned short h) {
    return __uint_as_float(((unsigned int)h) << 16);
}

__global__ __launch_bounds__(256) void vq_fused(const float* __restrict__ X,
                                                const float* __restrict__ E,
                                                float* __restrict__ out,
                                                int Ktot) {
    __shared__ unsigned short lds[2 * 128 * LSTR];   // A tile then B tile, 36864 B
    __shared__ float s_xsq[128];
    __shared__ float s_esq[128];

    const int tid = threadIdx.x;

    // ---- XCD-aware tile swizzle (bijective: 4096 % 8 == 0) ----
    const int nxb = Ktot >> 7;                 // tiles along K (8)
    const int cpx = gridDim.x >> 3;            // tiles per XCD (512)
    const int bid = blockIdx.x;
    const int swz = (bid & 7) * cpx + (bid >> 3);
    const int bx = swz % nxb;
    const int by = swz / nxb;
    const size_t m0 = (size_t)by * 128;
    const int n0 = bx * 128;

    unsigned short* ldsA = lds;
    unsigned short* ldsB = lds + 128 * LSTR;

    const float* gX = X + m0 * 64;
    const float* gE = E + (size_t)n0 * 64;

    // ---- stage: issue all 16 global float4 loads first (latency overlap) ----
    // 8 threads per row, 32 B (8 floats) per thread; 4 iters cover 128 rows.
    float4 v[8][2];
    #pragma unroll
    for (int it = 0; it < 4; ++it) {
        const int g = it * 256 + tid;
        const int row = g >> 3, c8 = (g & 7) * 8;
        const float* p = gX + row * 64 + c8;
        v[it][0] = *(const float4*)p;
        v[it][1] = *(const float4*)(p + 4);
        const float* q = gE + row * 64 + c8;
        v[4 + it][0] = *(const float4*)q;
        v[4 + it][1] = *(const float4*)(q + 4);
    }

    // ---- convert to bf16, write LDS, inline row-norm (8-lane reduce) ----
    #pragma unroll
    for (int half = 0; half < 2; ++half) {
        unsigned short* dst = half ? ldsB : ldsA;
        float* sq = half ? s_esq : s_xsq;
        #pragma unroll
        for (int it = 0; it < 4; ++it) {
            const int g = it * 256 + tid;
            const int row = g >> 3, c8 = (g & 7) * 8;
            const float* f = (const float*)&v[half * 4 + it][0];
            float s = 0.f;
            short8 pk;
            #pragma unroll
            for (int j = 0; j < 8; ++j) {
                const unsigned short h = f2bf(f[j]);
                const float r = bf2f(h);
                s = fmaf(r, r, s);          // norm from ROUNDED value
                pk[j] = (short)h;
            }
            *(short8*)&dst[row * LSTR + c8] = pk;
            s += __shfl_down(s, 4, 8);
            s += __shfl_down(s, 2, 8);
            s += __shfl_down(s, 1, 8);
            if ((tid & 7) == 0) sq[row] = s;
        }
    }
    __syncthreads();

    // ---- fragments from LDS ----
    const int w = tid >> 6;
    const int lane = tid & 63;
    const int quad = lane >> 4;
    const int l16 = lane & 15;
    const int wm = (w >> 1) * 64;
    const int wn = (w & 1) * 64;

    short8 a0[4], a1[4], b0[4], b1[4];
    #pragma unroll
    for (int t = 0; t < 4; ++t) {
        const int ar = wm + t * 16 + l16;
        a0[t] = *(const short8*)&ldsA[ar * LSTR + quad * 8];
        a1[t] = *(const short8*)&ldsA[ar * LSTR + 32 + quad * 8];
        const int br = wn + t * 16 + l16;
        b0[t] = *(const short8*)&ldsB[br * LSTR + quad * 8];
        b1[t] = *(const short8*)&ldsB[br * LSTR + 32 + quad * 8];
    }

    floatx4 acc[4][4];
    #pragma unroll
    for (int i = 0; i < 4; ++i)
        #pragma unroll
        for (int j = 0; j < 4; ++j)
            acc[i][j] = (floatx4){0.f, 0.f, 0.f, 0.f};

    // SWAPPED operands: D = E_frag x X_frag -> C/D row (quad*4+r) = output
    // COLUMN, C/D col (l16) = output ROW. Lane's 4 regs = 4 consecutive cols.
    #pragma unroll
    for (int i = 0; i < 4; ++i)
        #pragma unroll
        for (int j = 0; j < 4; ++j) {
            acc[i][j] = __builtin_amdgcn_mfma_f32_16x16x32_bf16(b0[j], a0[i], acc[i][j], 0, 0, 0);
            acc[i][j] = __builtin_amdgcn_mfma_f32_16x16x32_bf16(b1[j], a1[i], acc[i][j], 0, 0, 0);
        }

    // ---- epilogue: d = sqrt(max(xsq + esq - 2*cross, 0)), 16B nt stores ----
    #pragma unroll
    for (int i = 0; i < 4; ++i) {
        const int orow = wm + i * 16 + l16;          // output row for this lane
        const float xq = s_xsq[orow];
        float* op = out + (m0 + orow) * (size_t)Ktot + n0;
        #pragma unroll
        for (int j = 0; j < 4; ++j) {
            const int ncol0 = wn + j * 16 + quad * 4;   // 16B-aligned col base
            const floatx4 eqv = *(const floatx4*)&s_esq[ncol0];
            const floatx4 c = acc[i][j];
            floatx4 o;
            #pragma unroll
            for (int r = 0; r < 4; ++r)
                o[r] = __builtin_amdgcn_sqrtf(fmaxf(xq + eqv[r] - 2.0f * c[r], 0.0f));
            __builtin_nontemporal_store(o, (floatx4*)(op + ncol0));
        }
    }
}

extern "C" void kernel_launch(void* const* d_in, const int* in_sizes, int n_in,
                              void* d_out, int out_size, void* d_ws, size_t ws_size,
                              hipStream_t stream) {
    const float* X = (const float*)d_in[0];
    const float* E = (const float*)d_in[1];
    float* out = (float*)d_out;
    const int K = in_sizes[1] / 64;   // 1024

    const int tiles = (N_ROWS / 128) * (K / 128);   // 4096
    vq_fused<<<dim3(tiles), dim3(256), 0, stream>>>(X, E, out, K);
}

// Round 4
// 286.953 us; speedup vs baseline: 1.1007x; 1.0584x over previous
//
#include <hip/hip_runtime.h>

// VQ pairwise L2, single fused kernel: out[n,k] = ||X[n,:] - E[k,:]||.
// N=65536, K=1024, D=64. One 128x128 output tile per block (4 waves).
// fp32 X/E loaded directly (coalesced float4), converted fp32->bf16 in-reg
// (RNE), staged to padded LDS (stride 72 bf16 = 144 B); row sum-of-squares
// computed inline during staging (width-8 shuffle reduce); 16x16x32 bf16
// MFMA cross term with SWAPPED operands (E as A-operand, X as B-operand) so
// each lane's 4 acc regs are 4 consecutive OUTPUT COLUMNS -> vectorized
// 16B stores. R4 change: CACHED stores (no nontemporal) — nt bypassed L2
// write-combining; 64B half-line segments at 4KB stride ran the write path
// at ~2 TB/s vs the 6.4 TB/s the rocclr fill achieves through L2.
//
// XCD swizzle (T1): 4096 blocks, 8 XCDs; remap so each XCD gets a
// contiguous chunk of tile-space (X tiles read into ONE XCD L2).

typedef __attribute__((ext_vector_type(8))) short short8;    // 8 bf16 = 4 VGPR
typedef __attribute__((ext_vector_type(4))) float floatx4;   // MFMA C/D + stores

#define LSTR 72          // padded LDS row stride in bf16 elems (144 B)
#define N_ROWS 65536

__device__ __forceinline__ unsigned short f2bf(float f) {
    unsigned int u = __float_as_uint(f);
    u += 0x7FFFu + ((u >> 16) & 1u);     // round-to-nearest-even
    return (unsigned short)(u >> 16);
}
__device__ __forceinline__ float bf2f(unsigned short h) {
    return __uint_as_float(((unsigned int)h) << 16);
}

__global__ __launch_bounds__(256) void vq_fused(const float* __restrict__ X,
                                                const float* __restrict__ E,
                                                float* __restrict__ out,
                                                int Ktot) {
    __shared__ unsigned short lds[2 * 128 * LSTR];   // A tile then B tile, 36864 B
    __shared__ alignas(16) float s_xsq[128];
    __shared__ alignas(16) float s_esq[128];

    const int tid = threadIdx.x;

    // ---- XCD-aware tile swizzle (bijective: 4096 % 8 == 0) ----
    const int nxb = Ktot >> 7;                 // tiles along K (8)
    const int cpx = gridDim.x >> 3;            // tiles per XCD (512)
    const int bid = blockIdx.x;
    const int swz = (bid & 7) * cpx + (bid >> 3);
    const int bx = swz % nxb;
    const int by = swz / nxb;
    const size_t m0 = (size_t)by * 128;
    const int n0 = bx * 128;

    unsigned short* ldsA = lds;
    unsigned short* ldsB = lds + 128 * LSTR;

    const float* gX = X + m0 * 64;
    const float* gE = E + (size_t)n0 * 64;

    // ---- stage: issue all 16 global float4 loads first (latency overlap) ----
    // 8 threads per row, 32 B (8 floats) per thread; 4 iters cover 128 rows.
    float4 v[8][2];
    #pragma unroll
    for (int it = 0; it < 4; ++it) {
        const int g = it * 256 + tid;
        const int row = g >> 3, c8 = (g & 7) * 8;
        const float* p = gX + row * 64 + c8;
        v[it][0] = *(const float4*)p;
        v[it][1] = *(const float4*)(p + 4);
        const float* q = gE + row * 64 + c8;
        v[4 + it][0] = *(const float4*)q;
        v[4 + it][1] = *(const float4*)(q + 4);
    }

    // ---- convert to bf16, write LDS, inline row-norm (8-lane reduce) ----
    #pragma unroll
    for (int half = 0; half < 2; ++half) {
        unsigned short* dst = half ? ldsB : ldsA;
        float* sq = half ? s_esq : s_xsq;
        #pragma unroll
        for (int it = 0; it < 4; ++it) {
            const int g = it * 256 + tid;
            const int row = g >> 3, c8 = (g & 7) * 8;
            const float* f = (const float*)&v[half * 4 + it][0];
            float s = 0.f;
            short8 pk;
            #pragma unroll
            for (int j = 0; j < 8; ++j) {
                const unsigned short h = f2bf(f[j]);
                const float r = bf2f(h);
                s = fmaf(r, r, s);          // norm from ROUNDED value
                pk[j] = (short)h;
            }
            *(short8*)&dst[row * LSTR + c8] = pk;
            s += __shfl_down(s, 4, 8);
            s += __shfl_down(s, 2, 8);
            s += __shfl_down(s, 1, 8);
            if ((tid & 7) == 0) sq[row] = s;
        }
    }
    __syncthreads();

    // ---- fragments from LDS ----
    const int w = tid >> 6;
    const int lane = tid & 63;
    const int quad = lane >> 4;
    const int l16 = lane & 15;
    const int wm = (w >> 1) * 64;
    const int wn = (w & 1) * 64;

    short8 a0[4], a1[4], b0[4], b1[4];
    #pragma unroll
    for (int t = 0; t < 4; ++t) {
        const int ar = wm + t * 16 + l16;
        a0[t] = *(const short8*)&ldsA[ar * LSTR + quad * 8];
        a1[t] = *(const short8*)&ldsA[ar * LSTR + 32 + quad * 8];
        const int br = wn + t * 16 + l16;
        b0[t] = *(const short8*)&ldsB[br * LSTR + quad * 8];
        b1[t] = *(const short8*)&ldsB[br * LSTR + 32 + quad * 8];
    }

    floatx4 acc[4][4];
    #pragma unroll
    for (int i = 0; i < 4; ++i)
        #pragma unroll
        for (int j = 0; j < 4; ++j)
            acc[i][j] = (floatx4){0.f, 0.f, 0.f, 0.f};

    // SWAPPED operands: D = E_frag x X_frag -> C/D row (quad*4+r) = output
    // COLUMN, C/D col (l16) = output ROW. Lane's 4 regs = 4 consecutive cols.
    #pragma unroll
    for (int i = 0; i < 4; ++i)
        #pragma unroll
        for (int j = 0; j < 4; ++j) {
            acc[i][j] = __builtin_amdgcn_mfma_f32_16x16x32_bf16(b0[j], a0[i], acc[i][j], 0, 0, 0);
            acc[i][j] = __builtin_amdgcn_mfma_f32_16x16x32_bf16(b1[j], a1[i], acc[i][j], 0, 0, 0);
        }

    // ---- epilogue: d = sqrt(max(xsq + esq - 2*cross, 0)), 16B cached stores ----
    // j and j+1 instructions cover the two 64B halves of each 128B line
    // back-to-back; L2 write-back assembles full lines (no nt bypass).
    #pragma unroll
    for (int i = 0; i < 4; ++i) {
        const int orow = wm + i * 16 + l16;          // output row for this lane
        const float xq = s_xsq[orow];
        float* op = out + (m0 + orow) * (size_t)Ktot + n0;
        #pragma unroll
        for (int j = 0; j < 4; ++j) {
            const int ncol0 = wn + j * 16 + quad * 4;   // 16B-aligned col base
            const floatx4 eqv = *(const floatx4*)&s_esq[ncol0];
            const floatx4 c = acc[i][j];
            floatx4 o;
            #pragma unroll
            for (int r = 0; r < 4; ++r)
                o[r] = __builtin_amdgcn_sqrtf(fmaxf(xq + eqv[r] - 2.0f * c[r], 0.0f));
            *(floatx4*)(op + ncol0) = o;             // plain global_store_dwordx4
        }
    }
}

extern "C" void kernel_launch(void* const* d_in, const int* in_sizes, int n_in,
                              void* d_out, int out_size, void* d_ws, size_t ws_size,
                              hipStream_t stream) {
    const float* X = (const float*)d_in[0];
    const float* E = (const float*)d_in[1];
    float* out = (float*)d_out;
    const int K = in_sizes[1] / 64;   // 1024

    const int tiles = (N_ROWS / 128) * (K / 128);   // 4096
    vq_fused<<<dim3(tiles), dim3(256), 0, stream>>>(X, E, out, K);
}

// Round 6
// 284.110 us; speedup vs baseline: 1.1118x; 1.0100x over previous
//
#include <hip/hip_runtime.h>

// VQ pairwise L2, single fused kernel: out[n,k] = ||X[n,:] - E[k,:]||.
// N=65536, K=1024, D=64. One 128x128 output tile per block (4 waves).
// fp32 X/E loaded directly (coalesced float4), converted fp32->bf16 in-reg
// (RNE), staged to padded LDS (stride 72 bf16 = 144 B); row sum-of-squares
// inline during staging; 16x16x32 bf16 MFMA with SWAPPED operands (lane's
// 4 acc regs = 4 consecutive output cols).
//
// R5/R6 change (resubmit after infra failure): STORE-LINEAR epilogue. The
// MFMA C/D layout makes each store instruction touch 16 rows x 64B
// (scattered half-lines, 4KB apart). Now the epilogue routes through the
// dead staging LDS in 4x 16KB passes and drains in store-linear order:
// each global_store_dwordx4 writes 2 complete rows x 512B contiguous (full
// 128B lines only) — fill-like geometry. LDS chunks XOR-swizzled
// (chunk ^= row&7) -> near-conflict-free b128 on both sides.
//
// XCD swizzle (T1): 4096 blocks, 8 XCDs; contiguous tile chunk per XCD.

typedef __attribute__((ext_vector_type(8))) short short8;    // 8 bf16 = 4 VGPR
typedef __attribute__((ext_vector_type(4))) float floatx4;   // MFMA C/D + stores

#define LSTR 72          // padded LDS row stride in bf16 elems (144 B)
#define N_ROWS 65536

__device__ __forceinline__ unsigned short f2bf(float f) {
    unsigned int u = __float_as_uint(f);
    u += 0x7FFFu + ((u >> 16) & 1u);     // round-to-nearest-even
    return (unsigned short)(u >> 16);
}
__device__ __forceinline__ float bf2f(unsigned short h) {
    return __uint_as_float(((unsigned int)h) << 16);
}

__global__ __launch_bounds__(256) void vq_fused(const float* __restrict__ X,
                                                const float* __restrict__ E,
                                                float* __restrict__ out,
                                                int Ktot) {
    __shared__ alignas(16) unsigned short lds[2 * 128 * LSTR];   // 36864 B
    __shared__ alignas(16) float s_xsq[128];
    __shared__ alignas(16) float s_esq[128];

    const int tid = threadIdx.x;

    // ---- XCD-aware tile swizzle (bijective: 4096 % 8 == 0) ----
    const int nxb = Ktot >> 7;                 // tiles along K (8)
    const int cpx = gridDim.x >> 3;            // tiles per XCD (512)
    const int bid = blockIdx.x;
    const int swz = (bid & 7) * cpx + (bid >> 3);
    const int bx = swz % nxb;
    const int by = swz / nxb;
    const size_t m0 = (size_t)by * 128;
    const int n0 = bx * 128;

    unsigned short* ldsA = lds;
    unsigned short* ldsB = lds + 128 * LSTR;

    const float* gX = X + m0 * 64;
    const float* gE = E + (size_t)n0 * 64;

    // ---- stage: issue all 16 global float4 loads first (latency overlap) ----
    float4 v[8][2];
    #pragma unroll
    for (int it = 0; it < 4; ++it) {
        const int g = it * 256 + tid;
        const int row = g >> 3, c8 = (g & 7) * 8;
        const float* p = gX + row * 64 + c8;
        v[it][0] = *(const float4*)p;
        v[it][1] = *(const float4*)(p + 4);
        const float* q = gE + row * 64 + c8;
        v[4 + it][0] = *(const float4*)q;
        v[4 + it][1] = *(const float4*)(q + 4);
    }

    // ---- convert to bf16, write LDS, inline row-norm (8-lane reduce) ----
    #pragma unroll
    for (int half = 0; half < 2; ++half) {
        unsigned short* dst = half ? ldsB : ldsA;
        float* sq = half ? s_esq : s_xsq;
        #pragma unroll
        for (int it = 0; it < 4; ++it) {
            const int g = it * 256 + tid;
            const int row = g >> 3, c8 = (g & 7) * 8;
            const float* f = (const float*)&v[half * 4 + it][0];
            float s = 0.f;
            short8 pk;
            #pragma unroll
            for (int j = 0; j < 8; ++j) {
                const unsigned short h = f2bf(f[j]);
                const float r = bf2f(h);
                s = fmaf(r, r, s);          // norm from ROUNDED value
                pk[j] = (short)h;
            }
            *(short8*)&dst[row * LSTR + c8] = pk;
            s += __shfl_down(s, 4, 8);
            s += __shfl_down(s, 2, 8);
            s += __shfl_down(s, 1, 8);
            if ((tid & 7) == 0) sq[row] = s;
        }
    }
    __syncthreads();

    // ---- fragments from LDS ----
    const int w = tid >> 6;
    const int lane = tid & 63;
    const int quad = lane >> 4;
    const int l16 = lane & 15;
    const int wm = (w >> 1) * 64;
    const int wn = (w & 1) * 64;

    short8 a0[4], a1[4], b0[4], b1[4];
    #pragma unroll
    for (int t = 0; t < 4; ++t) {
        const int ar = wm + t * 16 + l16;
        a0[t] = *(const short8*)&ldsA[ar * LSTR + quad * 8];
        a1[t] = *(const short8*)&ldsA[ar * LSTR + 32 + quad * 8];
        const int br = wn + t * 16 + l16;
        b0[t] = *(const short8*)&ldsB[br * LSTR + quad * 8];
        b1[t] = *(const short8*)&ldsB[br * LSTR + 32 + quad * 8];
    }

    floatx4 acc[4][4];
    #pragma unroll
    for (int i = 0; i < 4; ++i)
        #pragma unroll
        for (int j = 0; j < 4; ++j)
            acc[i][j] = (floatx4){0.f, 0.f, 0.f, 0.f};

    // SWAPPED operands: C/D row (quad*4+r) = output COLUMN, col (l16) = ROW.
    #pragma unroll
    for (int i = 0; i < 4; ++i)
        #pragma unroll
        for (int j = 0; j < 4; ++j) {
            acc[i][j] = __builtin_amdgcn_mfma_f32_16x16x32_bf16(b0[j], a0[i], acc[i][j], 0, 0, 0);
            acc[i][j] = __builtin_amdgcn_mfma_f32_16x16x32_bf16(b1[j], a1[i], acc[i][j], 0, 0, 0);
        }

    // ---- epilogue: sqrt(max(xsq+esq-2c,0)) via LDS re-layout, linear stores ----
    // 4 passes; each pass: waves deposit a 32-row x 128-col f32 slab into LDS
    // (16KB, reusing staging LDS), barrier, then drain store-linear: each
    // store instruction = 2 complete rows x 512B contiguous (full lines).
    float* obuf = (float*)lds;              // [32][128] f32, 16B-chunk swizzled
    #pragma unroll
    for (int i = 0; i < 4; ++i) {
        __syncthreads();                    // slab buffer safe to (re)write
        {
            const int lr = (w >> 1) * 16 + l16;        // local slab row
            const int orow = wm + i * 16 + l16;        // tile row
            const float xq = s_xsq[orow];
            #pragma unroll
            for (int j = 0; j < 4; ++j) {
                const int ncol0 = wn + j * 16 + quad * 4;
                const int ch = ((ncol0 >> 2) ^ (lr & 7));   // 16B-chunk swizzle
                const floatx4 eqv = *(const floatx4*)&s_esq[ncol0];
                const floatx4 c = acc[i][j];
                floatx4 o;
                #pragma unroll
                for (int r = 0; r < 4; ++r)
                    o[r] = __builtin_amdgcn_sqrtf(fmaxf(xq + eqv[r] - 2.0f * c[r], 0.0f));
                *(floatx4*)&obuf[lr * 128 + ch * 4] = o;
            }
        }
        __syncthreads();
        // drain: lanes 0-31 = row lr2 cols 0-127, lanes 32-63 = row lr2+1
        #pragma unroll
        for (int s = 0; s < 4; ++s) {
            const int lr2 = w * 8 + s * 2 + (lane >> 5);
            const int c32 = lane & 31;                       // 16B chunk in row
            const int ch2 = c32 ^ (lr2 & 7);
            const floatx4 o = *(const floatx4*)&obuf[lr2 * 128 + ch2 * 4];
            const int grow = (lr2 >> 4) * 64 + i * 16 + (lr2 & 15);
            *(floatx4*)(out + (m0 + grow) * (size_t)Ktot + n0 + c32 * 4) = o;
        }
    }
}

extern "C" void kernel_launch(void* const* d_in, const int* in_sizes, int n_in,
                              void* d_out, int out_size, void* d_ws, size_t ws_size,
                              hipStream_t stream) {
    const float* X = (const float*)d_in[0];
    const float* E = (const float*)d_in[1];
    float* out = (float*)d_out;
    const int K = in_sizes[1] / 64;   // 1024

    const int tiles = (N_ROWS / 128) * (K / 128);   // 4096
    vq_fused<<<dim3(tiles), dim3(256), 0, stream>>>(X, E, out, K);
}

// Round 7
// 280.539 us; speedup vs baseline: 1.1259x; 1.0127x over previous
//
#include <hip/hip_runtime.h>

// VQ pairwise L2, single fused kernel: out[n,k] = ||X[n,:] - E[k,:]||.
// N=65536, K=1024, D=64. One 128x128 output tile per block (4 waves).
// fp32 X/E loaded directly (coalesced float4), converted fp32->bf16 in-reg
// (RNE), staged to padded LDS (stride 72 bf16 = 144 B); row sum-of-squares
// inline during staging; 16x16x32 bf16 MFMA with SWAPPED operands (lane's
// 4 acc regs = 4 consecutive output cols) -> direct 16B cached stores.
//
// R7 change: OCCUPANCY + PHASE INTERLEAVE. Previous versions peaked >128
// VGPR (64 staging + 64 fragments + 64 acc) -> 8 waves/CU = 2 blocks/CU
// (VGPR-bound, not LDS-bound), and each block's big end-of-block store
// drain phase-beat against the next block's load phase. Now:
//  - __launch_bounds__(256, 4): enforce <=128 VGPR -> 16 waves/CU =
//    4 blocks/CU (LDS limit, 37.9KB/block).
//  - strip-wise compute: one 16-row strip's acc (16 VGPR) at a time,
//    MFMA(8) -> store strip immediately; stores spread across the whole
//    block lifetime instead of a terminal drain. E fragments (32 VGPR)
//    resident; X fragments (8 VGPR) loaded per strip.
//
// XCD swizzle (T1): 4096 blocks, 8 XCDs; contiguous tile chunk per XCD.

typedef __attribute__((ext_vector_type(8))) short short8;    // 8 bf16 = 4 VGPR
typedef __attribute__((ext_vector_type(4))) float floatx4;   // MFMA C/D + stores

#define LSTR 72          // padded LDS row stride in bf16 elems (144 B)
#define N_ROWS 65536

__device__ __forceinline__ unsigned short f2bf(float f) {
    unsigned int u = __float_as_uint(f);
    u += 0x7FFFu + ((u >> 16) & 1u);     // round-to-nearest-even
    return (unsigned short)(u >> 16);
}
__device__ __forceinline__ float bf2f(unsigned short h) {
    return __uint_as_float(((unsigned int)h) << 16);
}

__global__ __launch_bounds__(256, 4) void vq_fused(const float* __restrict__ X,
                                                   const float* __restrict__ E,
                                                   float* __restrict__ out,
                                                   int Ktot) {
    __shared__ alignas(16) unsigned short lds[2 * 128 * LSTR];   // 36864 B
    __shared__ alignas(16) float s_xsq[128];
    __shared__ alignas(16) float s_esq[128];

    const int tid = threadIdx.x;

    // ---- XCD-aware tile swizzle (bijective: 4096 % 8 == 0) ----
    const int nxb = Ktot >> 7;                 // tiles along K (8)
    const int cpx = gridDim.x >> 3;            // tiles per XCD (512)
    const int bid = blockIdx.x;
    const int swz = (bid & 7) * cpx + (bid >> 3);
    const int bx = swz % nxb;
    const int by = swz / nxb;
    const size_t m0 = (size_t)by * 128;
    const int n0 = bx * 128;

    unsigned short* ldsA = lds;
    unsigned short* ldsB = lds + 128 * LSTR;

    const float* gX = X + m0 * 64;
    const float* gE = E + (size_t)n0 * 64;

    // ---- stage + convert, phase-split to keep VGPR low:
    // X: issue 8 float4 loads, convert, LDS-write; then E the same.
    // 4 blocks/CU x 4 waves of TLP hide the two exposed latency points.
    #pragma unroll
    for (int half = 0; half < 2; ++half) {
        const float* g = half ? gE : gX;
        unsigned short* dst = half ? ldsB : ldsA;
        float* sq = half ? s_esq : s_xsq;
        float4 v[4][2];
        #pragma unroll
        for (int it = 0; it < 4; ++it) {
            const int gg = it * 256 + tid;
            const int row = gg >> 3, c8 = (gg & 7) * 8;
            const float* p = g + row * 64 + c8;
            v[it][0] = *(const float4*)p;
            v[it][1] = *(const float4*)(p + 4);
        }
        #pragma unroll
        for (int it = 0; it < 4; ++it) {
            const int gg = it * 256 + tid;
            const int row = gg >> 3, c8 = (gg & 7) * 8;
            const float* f = (const float*)&v[it][0];
            float s = 0.f;
            short8 pk;
            #pragma unroll
            for (int j = 0; j < 8; ++j) {
                const unsigned short h = f2bf(f[j]);
                const float r = bf2f(h);
                s = fmaf(r, r, s);          // norm from ROUNDED value
                pk[j] = (short)h;
            }
            *(short8*)&dst[row * LSTR + c8] = pk;
            s += __shfl_down(s, 4, 8);
            s += __shfl_down(s, 2, 8);
            s += __shfl_down(s, 1, 8);
            if ((tid & 7) == 0) sq[row] = s;
        }
    }
    __syncthreads();

    // ---- per-wave geometry ----
    const int w = tid >> 6;
    const int lane = tid & 63;
    const int quad = lane >> 4;
    const int l16 = lane & 15;
    const int wm = (w >> 1) * 64;
    const int wn = (w & 1) * 64;

    // E fragments resident (32 VGPR)
    short8 b0[4], b1[4];
    #pragma unroll
    for (int t = 0; t < 4; ++t) {
        const int br = wn + t * 16 + l16;
        b0[t] = *(const short8*)&ldsB[br * LSTR + quad * 8];
        b1[t] = *(const short8*)&ldsB[br * LSTR + 32 + quad * 8];
    }

    // ---- strip-wise MFMA + immediate store (16 rows at a time) ----
    // SWAPPED operands: C/D col (l16) = output ROW, row (quad*4+r) = COLUMN.
    #pragma unroll
    for (int i = 0; i < 4; ++i) {
        const int ar = wm + i * 16 + l16;
        const short8 a0 = *(const short8*)&ldsA[ar * LSTR + quad * 8];
        const short8 a1 = *(const short8*)&ldsA[ar * LSTR + 32 + quad * 8];

        floatx4 acc[4];
        #pragma unroll
        for (int j = 0; j < 4; ++j) {
            acc[j] = __builtin_amdgcn_mfma_f32_16x16x32_bf16(
                b0[j], a0, (floatx4){0.f, 0.f, 0.f, 0.f}, 0, 0, 0);
            acc[j] = __builtin_amdgcn_mfma_f32_16x16x32_bf16(
                b1[j], a1, acc[j], 0, 0, 0);
        }

        const int orow = wm + i * 16 + l16;          // output row for this lane
        const float xq = s_xsq[orow];
        float* op = out + (m0 + orow) * (size_t)Ktot + n0;
        #pragma unroll
        for (int j = 0; j < 4; ++j) {
            const int ncol0 = wn + j * 16 + quad * 4;   // 16B-aligned col base
            const floatx4 eqv = *(const floatx4*)&s_esq[ncol0];
            const floatx4 c = acc[j];
            floatx4 o;
            #pragma unroll
            for (int r = 0; r < 4; ++r)
                o[r] = __builtin_amdgcn_sqrtf(fmaxf(xq + eqv[r] - 2.0f * c[r], 0.0f));
            *(floatx4*)(op + ncol0) = o;             // cached global_store_dwordx4
        }
    }
}

extern "C" void kernel_launch(void* const* d_in, const int* in_sizes, int n_in,
                              void* d_out, int out_size, void* d_ws, size_t ws_size,
                              hipStream_t stream) {
    const float* X = (const float*)d_in[0];
    const float* E = (const float*)d_in[1];
    float* out = (float*)d_out;
    const int K = in_sizes[1] / 64;   // 1024

    const int tiles = (N_ROWS / 128) * (K / 128);   // 4096
    vq_fused<<<dim3(tiles), dim3(256), 0, stream>>>(X, E, out, K);
}